// Round 2
// baseline (403.346 us; speedup 1.0000x reference)
//
#include <hip/hip_runtime.h>
#include <hip/hip_bf16.h>
#include <stdint.h>

typedef __attribute__((ext_vector_type(4))) float  f32x4;
typedef __attribute__((ext_vector_type(8))) short  short8;
typedef __attribute__((ext_vector_type(8))) __bf16 bf16x8;

#define GLB_AS __attribute__((address_space(1)))
#define LDS_AS __attribute__((address_space(3)))

__device__ __forceinline__ float bf2f(ushort u) {
    union { uint u32; float f; } c; c.u32 = (uint)u << 16; return c.f;
}
__device__ __forceinline__ ushort f2bf(float f) {
    union { float f; uint u32; } c; c.f = f;
    uint x = c.u32;
    return (ushort)((x + 0x7fffu + ((x >> 16) & 1u)) >> 16);
}

__device__ __forceinline__ void storeC(float* p, float v)  { *p = v; }
__device__ __forceinline__ void storeC(ushort* p, float v) { *p = f2bf(v); }

template<int N> __device__ __forceinline__ void vmwait() {
    if constexpr (N == 0) asm volatile("s_waitcnt vmcnt(0)" ::: "memory");
    else if constexpr (N == 2) asm volatile("s_waitcnt vmcnt(2)" ::: "memory");
    else if constexpr (N == 4) asm volatile("s_waitcnt vmcnt(4)" ::: "memory");
}

// ---------------- fp32 -> bf16 convert ----------------
__global__ __launch_bounds__(256) void convert_f32_bf16(
    const float* __restrict__ in, ushort* __restrict__ out, long n)
{
    long i0 = ((long)blockIdx.x * 256 + threadIdx.x) * 8;
    long stride = (long)gridDim.x * 256 * 8;
    for (long i = i0; i < n; i += stride) {
        float4 a = *(const float4*)(in + i);
        float4 b = *(const float4*)(in + i + 4);
        short8 o;
        o[0] = (short)f2bf(a.x); o[1] = (short)f2bf(a.y);
        o[2] = (short)f2bf(a.z); o[3] = (short)f2bf(a.w);
        o[4] = (short)f2bf(b.x); o[5] = (short)f2bf(b.y);
        o[6] = (short)f2bf(b.z); o[7] = (short)f2bf(b.w);
        *(short8*)(out + i) = o;
    }
}

// ---------------- RoPE in-place on fused QK buffer [8192][2048] ----------------
__global__ __launch_bounds__(256) void rope_inplace(
    ushort* __restrict__ qk, const float* __restrict__ pos)
{
    const int row = blockIdx.x;
    const float p = pos[row];
    const size_t base = (size_t)row * 2048;
    const int tid = threadIdx.x;
#pragma unroll
    for (int t = 0; t < 2; ++t) {
        int j = tid + t * 256;                       // pair index 0..511
        float omega = exp2f(-(float)j * (13.287712379549449f / 512.0f));
        float ang = p * omega;
        float sn, cs;
        sincosf(ang, &sn, &cs);
        uint pq = *(uint*)(qk + base + 2 * j);
        float q0 = bf2f((ushort)(pq & 0xffff)), q1 = bf2f((ushort)(pq >> 16));
        float r0 = q0 * cs - q1 * sn, r1 = q1 * cs + q0 * sn;
        *(uint*)(qk + base + 2 * j) = (uint)f2bf(r0) | ((uint)f2bf(r1) << 16);
        uint pk = *(uint*)(qk + base + 1024 + 2 * j);
        float k0 = bf2f((ushort)(pk & 0xffff)), k1 = bf2f((ushort)(pk >> 16));
        float s0 = k0 * cs - k1 * sn, s1 = k1 * cs + k0 * sn;
        *(uint*)(qk + base + 1024 + 2 * j) = (uint)f2bf(s0) | ((uint)f2bf(s1) << 16);
    }
}

// ---------------- row softmax over 2048 bf16, in place ----------------
__global__ __launch_bounds__(256) void softmax_rows(ushort* __restrict__ P)
{
    const size_t base = (size_t)blockIdx.x * 2048;
    const int tid = threadIdx.x;
    const int lane = tid & 63, wid = tid >> 6;
    short8 v = *(const short8*)(P + base + tid * 8);
    float f[8];
#pragma unroll
    for (int j = 0; j < 8; ++j) f[j] = bf2f((ushort)v[j]);
    float mx = f[0];
#pragma unroll
    for (int j = 1; j < 8; ++j) mx = fmaxf(mx, f[j]);
#pragma unroll
    for (int o = 32; o; o >>= 1) mx = fmaxf(mx, __shfl_xor(mx, o, 64));
    __shared__ float redm[4], reds[4];
    if (lane == 0) redm[wid] = mx;
    __syncthreads();
    mx = fmaxf(fmaxf(redm[0], redm[1]), fmaxf(redm[2], redm[3]));
    float s = 0.f;
#pragma unroll
    for (int j = 0; j < 8; ++j) { f[j] = __expf(f[j] - mx); s += f[j]; }
#pragma unroll
    for (int o = 32; o; o >>= 1) s += __shfl_xor(s, o, 64);
    if (lane == 0) reds[wid] = s;
    __syncthreads();
    s = reds[0] + reds[1] + reds[2] + reds[3];
    float inv = 1.0f / s;
    short8 o8;
#pragma unroll
    for (int j = 0; j < 8; ++j) o8[j] = (short)f2bf(f[j] * inv);
    *(short8*)(P + base + tid * 8) = o8;
}

// ================= 256x256 8-phase bf16 GEMM (C = A @ B^T) =================
// 512 thr / 8 waves (2M x 4N, interleaved quadrants), BK=64, dbuf LDS 128 KiB,
// st_16x32 swizzle (linear gload_lds dest + inverse-swizzled global src),
// counted vmcnt(4) per phase (never drains in main loop), setprio on MFMA.

// stage one 128x64 half-tile (16 KB): 2 x global_load_lds(16B) per thread
template<int C, int H>
__device__ __forceinline__ void stageT(ushort (&L)[2][2][8192],
    const ushort* __restrict__ G, int tileBase, int ld, int t,
    int wid, int sr, int scS)
{
#pragma unroll
    for (int i = 0; i < 2; ++i) {
        const int row = (wid * 2 + i) * 8 + sr;
        const ushort* g = G + (size_t)(tileBase + H * 128 + row) * ld + t * 64 + scS * 8;
        __builtin_amdgcn_global_load_lds((const GLB_AS void*)g,
            (LDS_AS void*)(&L[C][H][(wid * 2 + i) * 512]), 16, 0, 0);
    }
}

template<int C, int H>
__device__ __forceinline__ void readA(const ushort (&As)[2][2][8192],
    short8 (&afr)[4][2], int wr, int fr, int kg)
{
#pragma unroll
    for (int m = 0; m < 4; ++m) {
        const int r = wr * 64 + m * 16 + fr;
        const int sw = ((r >> 2) & 1) << 4;
#pragma unroll
        for (int kk = 0; kk < 2; ++kk)
            afr[m][kk] = *(const short8*)&As[C][H][r * 64 + ((kk * 32 + kg * 8) ^ sw)];
    }
}

template<int C, int H>
__device__ __forceinline__ void readB(const ushort (&Bs)[2][2][8192],
    short8 (&bfr)[2][2], int wc, int fr, int kg)
{
#pragma unroll
    for (int n = 0; n < 2; ++n) {
        const int r = wc * 32 + n * 16 + fr;
        const int sw = ((r >> 2) & 1) << 4;
#pragma unroll
        for (int kk = 0; kk < 2; ++kk)
            bfr[n][kk] = *(const short8*)&Bs[C][H][r * 64 + ((kk * 32 + kg * 8) ^ sw)];
    }
}

template<int MQ, int NQ>
__device__ __forceinline__ void domfma(f32x4 (&acc)[2][2][4][2],
    const short8 (&afr)[4][2], const short8 (&bfr)[2][2])
{
#pragma unroll
    for (int kk = 0; kk < 2; ++kk)
#pragma unroll
        for (int m = 0; m < 4; ++m)
#pragma unroll
            for (int n = 0; n < 2; ++n)
                acc[MQ][NQ][m][n] = __builtin_amdgcn_mfma_f32_16x16x32_bf16(
                    __builtin_bit_cast(bf16x8, afr[m][kk]),
                    __builtin_bit_cast(bf16x8, bfr[n][kk]),
                    acc[MQ][NQ][m][n], 0, 0, 0);
}

#define PHASE_MID() \
    __builtin_amdgcn_s_barrier(); \
    asm volatile("s_waitcnt lgkmcnt(0)" ::: "memory"); \
    __builtin_amdgcn_s_setprio(1)
#define PHASE_END(VM) \
    __builtin_amdgcn_s_setprio(0); \
    vmwait<VM>(); \
    __builtin_amdgcn_s_barrier()

// compute tile (buffer C); stage tile tNext into buffer C^1 unless LAST.
// stage order [B0,A0,A1,B1] + vmcnt(4)-per-phase guarantees each half lands
// (for every wave) before the barrier preceding its first read.
template<int C, bool LAST>
__device__ __forceinline__ void tile_body(
    ushort (&As)[2][2][8192], ushort (&Bs)[2][2][8192],
    f32x4 (&acc)[2][2][4][2],
    const ushort* __restrict__ A, const ushort* __restrict__ B,
    int rowBase, int colBase, int lda, int ldb, int tNext,
    int wid, int wr, int wc, int fr, int kg, int sr, int scS)
{
    short8 afr[4][2], bfr[2][2];
    // p1: quadrant (0,0)
    readA<C, 0>(As, afr, wr, fr, kg);
    readB<C, 0>(Bs, bfr, wc, fr, kg);
    if constexpr (!LAST) stageT<C ^ 1, 0>(Bs, B, colBase, ldb, tNext, wid, sr, scS);
    PHASE_MID();
    domfma<0, 0>(acc, afr, bfr);
    PHASE_END((LAST ? 2 : 4));
    // p2: quadrant (1,0)
    readA<C, 1>(As, afr, wr, fr, kg);
    if constexpr (!LAST) stageT<C ^ 1, 0>(As, A, rowBase, lda, tNext, wid, sr, scS);
    PHASE_MID();
    domfma<1, 0>(acc, afr, bfr);
    PHASE_END((LAST ? 0 : 4));
    // p3: quadrant (1,1)
    readB<C, 1>(Bs, bfr, wc, fr, kg);
    if constexpr (!LAST) stageT<C ^ 1, 1>(As, A, rowBase, lda, tNext, wid, sr, scS);
    PHASE_MID();
    domfma<1, 1>(acc, afr, bfr);
    PHASE_END((LAST ? 0 : 4));
    // p4: quadrant (0,1)
    readA<C, 0>(As, afr, wr, fr, kg);
    if constexpr (!LAST) stageT<C ^ 1, 1>(Bs, B, colBase, ldb, tNext, wid, sr, scS);
    PHASE_MID();
    domfma<0, 1>(acc, afr, bfr);
    PHASE_END((LAST ? 0 : 4));
}

template<bool BIAS_COL, bool BIAS_ROW, bool CAUSAL_MASK, bool CAUSAL_K, typename OutT>
__global__ __launch_bounds__(512, 2) void gemm256(
    const ushort* __restrict__ A, const ushort* __restrict__ B,
    OutT* __restrict__ C, const float* __restrict__ bias,
    int K, int lda, int ldb, int ldc,
    long sA, long sB, long sC, float scale)
{
    __shared__ ushort As[2][2][8192];   // [dbuf][half: tile rows 0-127/128-255][128r x 64k]
    __shared__ ushort Bs[2][2][8192];
    A += (long)blockIdx.z * sA;
    B += (long)blockIdx.z * sB;
    C += (long)blockIdx.z * sC;
    const int tid = threadIdx.x;
    const int lane = tid & 63;
    const int wid = tid >> 6;
    const int wr = wid >> 2, wc = wid & 3;    // 2M x 4N waves
    const int rowBase = blockIdx.y * 256;
    const int colBase = blockIdx.x * 256;
    const int fr = lane & 15;
    const int kg = lane >> 4;

    f32x4 acc[2][2][4][2] = {};

    const bool skip = CAUSAL_MASK && (colBase > rowBase + 255);
    int Kend = K;
    if (CAUSAL_K) { int ke = rowBase + 256; Kend = ke < K ? ke : K; }

    if (!skip) {
        const int sr = lane >> 3;                                  // row in 8-row seg
        const int scS = (lane & 7) ^ (((lane >> 5) & 1) << 1);     // inverse-swizzled src chunk
        // prologue: tile 0 -> buf 0
        stageT<0, 0>(Bs, B, colBase, ldb, 0, wid, sr, scS);
        stageT<0, 0>(As, A, rowBase, lda, 0, wid, sr, scS);
        stageT<0, 1>(As, A, rowBase, lda, 0, wid, sr, scS);
        stageT<0, 1>(Bs, B, colBase, ldb, 0, wid, sr, scS);
        vmwait<0>();
        __builtin_amdgcn_s_barrier();

        const int NT = Kend >> 6;   // always even here (K multiples of 128)
        int t = 0;
        for (; t + 2 < NT; t += 2) {
            tile_body<0, false>(As, Bs, acc, A, B, rowBase, colBase, lda, ldb, t + 1,
                                wid, wr, wc, fr, kg, sr, scS);
            tile_body<1, false>(As, Bs, acc, A, B, rowBase, colBase, lda, ldb, t + 2,
                                wid, wr, wc, fr, kg, sr, scS);
        }
        tile_body<0, false>(As, Bs, acc, A, B, rowBase, colBase, lda, ldb, t + 1,
                            wid, wr, wc, fr, kg, sr, scS);
        tile_body<1, true>(As, Bs, acc, A, B, rowBase, colBase, lda, ldb, 0,
                           wid, wr, wc, fr, kg, sr, scS);
    }

    // epilogue: C/D frag layout col = lane&15, row = (lane>>4)*4 + j
#pragma unroll
    for (int mq = 0; mq < 2; ++mq)
#pragma unroll
        for (int nq = 0; nq < 2; ++nq)
#pragma unroll
            for (int m = 0; m < 4; ++m)
#pragma unroll
                for (int n = 0; n < 2; ++n)
#pragma unroll
                    for (int j = 0; j < 4; ++j) {
                        int row = rowBase + mq * 128 + wr * 64 + m * 16 + kg * 4 + j;
                        int col = colBase + nq * 128 + wc * 32 + n * 16 + fr;
                        float v = acc[mq][nq][m][n][j] * scale;
                        if (BIAS_COL) v += bias[col];
                        if (BIAS_ROW) v += bias[row];
                        if (CAUSAL_MASK && (col > row)) v = -1e7f;
                        storeC(C + (size_t)row * ldc + col, v);
                    }
}

// ---------------- host-side orchestration ----------------
extern "C" void kernel_launch(void* const* d_in, const int* in_sizes, int n_in,
                              void* d_out, int out_size, void* d_ws, size_t ws_size,
                              hipStream_t stream)
{
    const float* x   = (const float*)d_in[0];
    const float* pos = (const float*)d_in[1];
    // d_in[2] = mask (causal, known analytically) — unused
    const float* Wq = (const float*)d_in[3]; const float* bq = (const float*)d_in[4];
    const float* Wk = (const float*)d_in[5]; const float* bk = (const float*)d_in[6];
    const float* Wv = (const float*)d_in[7]; const float* bv = (const float*)d_in[8];
    const float* Wo = (const float*)d_in[9]; const float* bo = (const float*)d_in[10];
    float* out = (float*)d_out;

    const int S = 2048, E = 1024, H = 1024, Bz = 4;
    const int Mtot = Bz * S;   // 8192

    ushort* xb   = (ushort*)d_ws;              // 8192x1024 (reused as O later)
    ushort* wqkb = xb   + (size_t)Mtot * E;    // 2048x1024 (Wq rows 0-1023, Wk rows 1024-2047)
    ushort* wvb  = wqkb + (size_t)2 * H * E;
    ushort* wob  = wvb  + (size_t)H * E;
    ushort* qk   = wob  + (size_t)H * H;       // 8192x2048 (Q cols 0-1023, K cols 1024-2047)
    ushort* vt   = qk   + (size_t)Mtot * 2 * H;// 1024 x 8192  (VT[h][b*S+s])
    ushort* P    = vt   + (size_t)H * Mtot;    // 4 x 2048 x 2048
    float*  bqk  = (float*)(P + (size_t)Bz * S * S); // 2048 fp32
    ushort* O    = xb;                         // reuse (xb dead after VT-proj)

    convert_f32_bf16<<<2048, 256, 0, stream>>>(x,  xb,   (long)Mtot * E);
    convert_f32_bf16<<<512,  256, 0, stream>>>(Wq, wqkb, (long)H * E);
    convert_f32_bf16<<<512,  256, 0, stream>>>(Wk, wqkb + (size_t)H * E, (long)H * E);
    convert_f32_bf16<<<512,  256, 0, stream>>>(Wv, wvb,  (long)H * E);
    convert_f32_bf16<<<512,  256, 0, stream>>>(Wo, wob,  (long)H * H);
    hipMemcpyAsync(bqk,     bq, H * sizeof(float), hipMemcpyDeviceToDevice, stream);
    hipMemcpyAsync(bqk + H, bk, H * sizeof(float), hipMemcpyDeviceToDevice, stream);

    // fused [Q|K] = x @ [Wq|Wk]^T + [bq|bk]   (256 blocks = full GPU)
    gemm256<true, false, false, false, ushort><<<dim3(8, 32, 1), 512, 0, stream>>>(
        xb, wqkb, qk, bqk, E, E, E, 2 * H, 0, 0, 0, 1.0f);
    // VT = Wv @ x^T + bv(row)  -> V transposed for free
    gemm256<false, true, false, false, ushort><<<dim3(32, 4, 1), 512, 0, stream>>>(
        wvb, xb, vt, bv, E, E, E, Mtot, 0, 0, 0, 1.0f);

    rope_inplace<<<Mtot, 256, 0, stream>>>(qk, pos);

    // P = causal_mask(Q@K^T / 32)
    gemm256<false, false, true, false, ushort><<<dim3(8, 8, Bz), 512, 0, stream>>>(
        qk, qk + H, P, nullptr, H, 2 * H, 2 * H, S,
        (long)S * 2 * H, (long)S * 2 * H, (long)S * S, 0.03125f);

    softmax_rows<<<Mtot, 256, 0, stream>>>(P);

    // O = P @ VT^T  (K clipped by causality to rowBase+256)
    gemm256<false, false, false, true, ushort><<<dim3(4, 8, Bz), 512, 0, stream>>>(
        P, vt, O, nullptr, S, S, Mtot, H,
        (long)S * S, (long)S, (long)S * H, 1.0f);

    // out = O @ Wo^T + bo  (fp32 -> d_out)
    gemm256<true, false, false, false, float><<<dim3(4, 32, 1), 512, 0, stream>>>(
        O, wob, out, bo, H, H, H, H, 0, 0, 0, 1.0f);
}

// Round 3
// 382.507 us; speedup vs baseline: 1.0545x; 1.0545x over previous
//
#include <hip/hip_runtime.h>
#include <hip/hip_bf16.h>
#include <stdint.h>

typedef __attribute__((ext_vector_type(4))) float  f32x4;
typedef __attribute__((ext_vector_type(8))) short  short8;
typedef __attribute__((ext_vector_type(8))) __bf16 bf16x8;

#define GLB_AS __attribute__((address_space(1)))
#define LDS_AS __attribute__((address_space(3)))

__device__ __forceinline__ float bf2f(ushort u) {
    union { uint u32; float f; } c; c.u32 = (uint)u << 16; return c.f;
}
__device__ __forceinline__ ushort f2bf(float f) {
    union { float f; uint u32; } c; c.f = f;
    uint x = c.u32;
    return (ushort)((x + 0x7fffu + ((x >> 16) & 1u)) >> 16);
}

__device__ __forceinline__ void storeC(float* p, float v)  { *p = v; }
__device__ __forceinline__ void storeC(ushort* p, float v) { *p = f2bf(v); }

template<int N> __device__ __forceinline__ void vmwait() {
    if constexpr (N == 0) asm volatile("s_waitcnt vmcnt(0)" ::: "memory");
    else if constexpr (N == 6) asm volatile("s_waitcnt vmcnt(6)" ::: "memory");
}

// ---------------- fp32 -> bf16 convert ----------------
__global__ __launch_bounds__(256) void convert_f32_bf16(
    const float* __restrict__ in, ushort* __restrict__ out, long n)
{
    long i0 = ((long)blockIdx.x * 256 + threadIdx.x) * 8;
    long stride = (long)gridDim.x * 256 * 8;
    for (long i = i0; i < n; i += stride) {
        float4 a = *(const float4*)(in + i);
        float4 b = *(const float4*)(in + i + 4);
        short8 o;
        o[0] = (short)f2bf(a.x); o[1] = (short)f2bf(a.y);
        o[2] = (short)f2bf(a.z); o[3] = (short)f2bf(a.w);
        o[4] = (short)f2bf(b.x); o[5] = (short)f2bf(b.y);
        o[6] = (short)f2bf(b.z); o[7] = (short)f2bf(b.w);
        *(short8*)(out + i) = o;
    }
}

// ---------------- RoPE in-place on fused QK buffer [8192][2048] ----------------
__global__ __launch_bounds__(256) void rope_inplace(
    ushort* __restrict__ qk, const float* __restrict__ pos)
{
    const int row = blockIdx.x;
    const float p = pos[row];
    const size_t base = (size_t)row * 2048;
    const int tid = threadIdx.x;
#pragma unroll
    for (int t = 0; t < 2; ++t) {
        int j = tid + t * 256;                       // pair index 0..511
        float omega = exp2f(-(float)j * (13.287712379549449f / 512.0f));
        float ang = p * omega;
        float sn, cs;
        sincosf(ang, &sn, &cs);
        uint pq = *(uint*)(qk + base + 2 * j);
        float q0 = bf2f((ushort)(pq & 0xffff)), q1 = bf2f((ushort)(pq >> 16));
        float r0 = q0 * cs - q1 * sn, r1 = q1 * cs + q0 * sn;
        *(uint*)(qk + base + 2 * j) = (uint)f2bf(r0) | ((uint)f2bf(r1) << 16);
        uint pk = *(uint*)(qk + base + 1024 + 2 * j);
        float k0 = bf2f((ushort)(pk & 0xffff)), k1 = bf2f((ushort)(pk >> 16));
        float s0 = k0 * cs - k1 * sn, s1 = k1 * cs + k0 * sn;
        *(uint*)(qk + base + 1024 + 2 * j) = (uint)f2bf(s0) | ((uint)f2bf(s1) << 16);
    }
}

// ---------------- row softmax over 2048 bf16, in place ----------------
__global__ __launch_bounds__(256) void softmax_rows(ushort* __restrict__ P)
{
    const size_t base = (size_t)blockIdx.x * 2048;
    const int tid = threadIdx.x;
    const int lane = tid & 63, wid = tid >> 6;
    short8 v = *(const short8*)(P + base + tid * 8);
    float f[8];
#pragma unroll
    for (int j = 0; j < 8; ++j) f[j] = bf2f((ushort)v[j]);
    float mx = f[0];
#pragma unroll
    for (int j = 1; j < 8; ++j) mx = fmaxf(mx, f[j]);
#pragma unroll
    for (int o = 32; o; o >>= 1) mx = fmaxf(mx, __shfl_xor(mx, o, 64));
    __shared__ float redm[4], reds[4];
    if (lane == 0) redm[wid] = mx;
    __syncthreads();
    mx = fmaxf(fmaxf(redm[0], redm[1]), fmaxf(redm[2], redm[3]));
    float s = 0.f;
#pragma unroll
    for (int j = 0; j < 8; ++j) { f[j] = __expf(f[j] - mx); s += f[j]; }
#pragma unroll
    for (int o = 32; o; o >>= 1) s += __shfl_xor(s, o, 64);
    if (lane == 0) reds[wid] = s;
    __syncthreads();
    s = reds[0] + reds[1] + reds[2] + reds[3];
    float inv = 1.0f / s;
    short8 o8;
#pragma unroll
    for (int j = 0; j < 8; ++j) o8[j] = (short)f2bf(f[j] * inv);
    *(short8*)(P + base + tid * 8) = o8;
}

// ================= 256x256 8-phase bf16 GEMM (C = A @ B^T) =================
// 512 thr / 8 waves (2M x 4N). BK=64. Double-buffered 128 KiB LDS.
// 3-bit XOR swizzle: LDS slot (row, 16B-chunk j) holds global chunk j^(row&7)
// (linear gload_lds dest + inverse-swizzled global src; reads XOR the same).
// Schedule per group (tile t, buf=t&1), one stage per phase into just-freed
// region; ONE vmcnt(6) per tile at p4 (stage->wait distance 3-7 phases):
//   p1: rd A0,B0 | stage A0(t+1)->buf^1      | bar; lgkm0; MFMA(0,0); bar
//   p2: rd A1    | stage B0(t+2)->buf.B0     | bar; lgkm0; MFMA(1,0); bar
//   p3: rd B1    | stage A1(t+2)->buf.A1     | bar; lgkm0; MFMA(1,1); bar
//   p4: rd A0    | stage B1(t+2)->buf.B1     | bar; lgkm0; MFMA(0,1); vmcnt(6); bar
// Ledger: at [t,p4] vmcnt(6) the 3 youngest halves are exactly {B0,A1,B1}(t+2),
// so ALL of tile t+1 has landed before group t+1 reads it. Tail: vmcnt(0) at
// group NT-2, no stages/waits at NT-1.

template<int BUF, int HALF>
__device__ __forceinline__ void stageT(ushort (&L)[2][2][8192],
    const ushort* __restrict__ G, int tileBase, int ld, int tk,
    int wid, int sr, int scS)
{
#pragma unroll
    for (int i = 0; i < 2; ++i) {
        const int chunk = wid * 2 + i;
        const ushort* g = G + (size_t)(tileBase + HALF * 128 + chunk * 8 + sr) * ld
                        + tk * 64 + scS * 8;
        __builtin_amdgcn_global_load_lds((const GLB_AS void*)g,
            (LDS_AS void*)(&L[BUF][HALF][chunk * 512]), 16, 0, 0);
    }
}

template<int BUF, int HALF>
__device__ __forceinline__ void readA(const ushort (&As)[2][2][8192],
    short8 (&afr)[4][2], int wr, int fr, int kg)
{
    const int sw = (fr & 7) << 3;
#pragma unroll
    for (int m = 0; m < 4; ++m) {
        const int r = wr * 64 + m * 16 + fr;
#pragma unroll
        for (int kk = 0; kk < 2; ++kk)
            afr[m][kk] = *(const short8*)&As[BUF][HALF][r * 64 + ((kk * 32 + kg * 8) ^ sw)];
    }
}

template<int BUF, int HALF>
__device__ __forceinline__ void readB(const ushort (&Bs)[2][2][8192],
    short8 (&bfr)[2][2], int wc, int fr, int kg)
{
    const int sw = (fr & 7) << 3;
#pragma unroll
    for (int n = 0; n < 2; ++n) {
        const int r = wc * 32 + n * 16 + fr;
#pragma unroll
        for (int kk = 0; kk < 2; ++kk)
            bfr[n][kk] = *(const short8*)&Bs[BUF][HALF][r * 64 + ((kk * 32 + kg * 8) ^ sw)];
    }
}

template<int MQ, int NQ>
__device__ __forceinline__ void domfma(f32x4 (&acc)[2][2][4][2],
    const short8 (&afr)[4][2], const short8 (&bfr)[2][2])
{
#pragma unroll
    for (int kk = 0; kk < 2; ++kk)
#pragma unroll
        for (int m = 0; m < 4; ++m)
#pragma unroll
            for (int n = 0; n < 2; ++n)
                acc[MQ][NQ][m][n] = __builtin_amdgcn_mfma_f32_16x16x32_bf16(
                    __builtin_bit_cast(bf16x8, afr[m][kk]),
                    __builtin_bit_cast(bf16x8, bfr[n][kk]),
                    acc[MQ][NQ][m][n], 0, 0, 0);
}

#define PHASE_MID() \
    __builtin_amdgcn_s_barrier(); \
    asm volatile("s_waitcnt lgkmcnt(0)" ::: "memory"); \
    __builtin_amdgcn_sched_barrier(0); \
    __builtin_amdgcn_s_setprio(1)
#define PHASE_END() \
    __builtin_amdgcn_s_setprio(0); \
    __builtin_amdgcn_s_barrier()

// MODE: 0 = FULL (stage A0(t+1) + tile t+2, vmcnt(6))
//       1 = PRELAST (stage A0(t+1) only, vmcnt(0))
//       2 = LAST (no stages, no waits)
template<int BUF, int MODE>
__device__ __forceinline__ void group(
    ushort (&As)[2][2][8192], ushort (&Bs)[2][2][8192],
    f32x4 (&acc)[2][2][4][2],
    const ushort* __restrict__ A, const ushort* __restrict__ B,
    int rowBase, int colBase, int lda, int ldb, int t,
    int wid, int wr, int wc, int fr, int kg, int sr, int scS)
{
    short8 afr[4][2], bfr[2][2];
    // p1
    readA<BUF, 0>(As, afr, wr, fr, kg);
    readB<BUF, 0>(Bs, bfr, wc, fr, kg);
    if constexpr (MODE != 2) stageT<BUF ^ 1, 0>(As, A, rowBase, lda, t + 1, wid, sr, scS);
    asm volatile("s_waitcnt lgkmcnt(8)" ::: "memory");
    PHASE_MID();
    domfma<0, 0>(acc, afr, bfr);
    PHASE_END();
    // p2
    readA<BUF, 1>(As, afr, wr, fr, kg);
    if constexpr (MODE == 0) stageT<BUF, 0>(Bs, B, colBase, ldb, t + 2, wid, sr, scS);
    PHASE_MID();
    domfma<1, 0>(acc, afr, bfr);
    PHASE_END();
    // p3
    readB<BUF, 1>(Bs, bfr, wc, fr, kg);
    if constexpr (MODE == 0) stageT<BUF, 1>(As, A, rowBase, lda, t + 2, wid, sr, scS);
    PHASE_MID();
    domfma<1, 1>(acc, afr, bfr);
    PHASE_END();
    // p4
    readA<BUF, 0>(As, afr, wr, fr, kg);
    if constexpr (MODE == 0) stageT<BUF, 1>(Bs, B, colBase, ldb, t + 2, wid, sr, scS);
    PHASE_MID();
    domfma<0, 1>(acc, afr, bfr);
    __builtin_amdgcn_s_setprio(0);
    if constexpr (MODE == 0) vmwait<6>();
    else if constexpr (MODE == 1) vmwait<0>();
    __builtin_amdgcn_s_barrier();
}

template<bool BIAS_COL, bool BIAS_ROW, bool CAUSAL_MASK, bool CAUSAL_K, typename OutT>
__global__ __launch_bounds__(512, 2) void gemm256(
    const ushort* __restrict__ A, const ushort* __restrict__ B,
    OutT* __restrict__ C, const float* __restrict__ bias,
    int K, int lda, int ldb, int ldc,
    long sA, long sB, long sC, float scale)
{
    __shared__ ushort As[2][2][8192];   // [dbuf][half: rows 0-127 / 128-255][128r x 64k]
    __shared__ ushort Bs[2][2][8192];

    // T1: bijective XCD swizzle (all grids have nwg % 8 == 0)
    const int nx = gridDim.x, ny = gridDim.y;
    int flat = blockIdx.x + nx * (blockIdx.y + ny * blockIdx.z);
    const int nwg = nx * ny * gridDim.z;
    const int qq = nwg >> 3;
    int swz = (flat & 7) * qq + (flat >> 3);
    const int bx = swz % nx;
    int rest = swz / nx;
    const int by = rest % ny;
    const int bz = rest / ny;

    A += (long)bz * sA;
    B += (long)bz * sB;
    C += (long)bz * sC;
    const int tid = threadIdx.x;
    const int lane = tid & 63;
    const int wid = tid >> 6;
    const int wr = wid >> 2, wc = wid & 3;    // 2M x 4N waves
    const int rowBase = by * 256;
    const int colBase = bx * 256;
    const int fr = lane & 15;
    const int kg = lane >> 4;

    f32x4 acc[2][2][4][2] = {};

    const bool skip = CAUSAL_MASK && (colBase > rowBase + 255);
    int Kend = K;
    if (CAUSAL_K) { int ke = rowBase + 256; Kend = ke < K ? ke : K; }

    if (!skip) {
        const int sr = lane >> 3;                  // row within 8-row chunk
        const int scS = (lane & 7) ^ (lane >> 3);  // inverse-swizzled src 16B-chunk
        // prologue: tile 0 fully + B0,A1,B1 of tile 1  (A0(1) staged at [0,p1])
        stageT<0, 0>(As, A, rowBase, lda, 0, wid, sr, scS);
        stageT<0, 0>(Bs, B, colBase, ldb, 0, wid, sr, scS);
        stageT<0, 1>(As, A, rowBase, lda, 0, wid, sr, scS);
        stageT<0, 1>(Bs, B, colBase, ldb, 0, wid, sr, scS);
        stageT<1, 0>(Bs, B, colBase, ldb, 1, wid, sr, scS);
        stageT<1, 1>(As, A, rowBase, lda, 1, wid, sr, scS);
        stageT<1, 1>(Bs, B, colBase, ldb, 1, wid, sr, scS);
        vmwait<6>();                               // tile 0 fully landed
        __builtin_amdgcn_s_barrier();

        const int NT = Kend >> 6;                  // even, >= 2 for all our shapes
        int t = 0;
        for (; t + 3 < NT; t += 2) {
            group<0, 0>(As, Bs, acc, A, B, rowBase, colBase, lda, ldb, t,
                        wid, wr, wc, fr, kg, sr, scS);
            group<1, 0>(As, Bs, acc, A, B, rowBase, colBase, lda, ldb, t + 1,
                        wid, wr, wc, fr, kg, sr, scS);
        }
        group<0, 1>(As, Bs, acc, A, B, rowBase, colBase, lda, ldb, t,
                    wid, wr, wc, fr, kg, sr, scS);
        group<1, 2>(As, Bs, acc, A, B, rowBase, colBase, lda, ldb, t + 1,
                    wid, wr, wc, fr, kg, sr, scS);
    }

    // epilogue: C/D frag layout col = lane&15, row = (lane>>4)*4 + j
#pragma unroll
    for (int mq = 0; mq < 2; ++mq)
#pragma unroll
        for (int nq = 0; nq < 2; ++nq)
#pragma unroll
            for (int m = 0; m < 4; ++m)
#pragma unroll
                for (int n = 0; n < 2; ++n)
#pragma unroll
                    for (int j = 0; j < 4; ++j) {
                        int row = rowBase + mq * 128 + wr * 64 + m * 16 + kg * 4 + j;
                        int col = colBase + nq * 128 + wc * 32 + n * 16 + fr;
                        float v = acc[mq][nq][m][n][j] * scale;
                        if (BIAS_COL) v += bias[col];
                        if (BIAS_ROW) v += bias[row];
                        if (CAUSAL_MASK && (col > row)) v = -1e7f;
                        storeC(C + (size_t)row * ldc + col, v);
                    }
}

// ---------------- host-side orchestration ----------------
extern "C" void kernel_launch(void* const* d_in, const int* in_sizes, int n_in,
                              void* d_out, int out_size, void* d_ws, size_t ws_size,
                              hipStream_t stream)
{
    const float* x   = (const float*)d_in[0];
    const float* pos = (const float*)d_in[1];
    // d_in[2] = mask (causal, known analytically) — unused
    const float* Wq = (const float*)d_in[3]; const float* bq = (const float*)d_in[4];
    const float* Wk = (const float*)d_in[5]; const float* bk = (const float*)d_in[6];
    const float* Wv = (const float*)d_in[7]; const float* bv = (const float*)d_in[8];
    const float* Wo = (const float*)d_in[9]; const float* bo = (const float*)d_in[10];
    float* out = (float*)d_out;

    const int S = 2048, E = 1024, H = 1024, Bz = 4;
    const int Mtot = Bz * S;   // 8192

    ushort* xb   = (ushort*)d_ws;              // 8192x1024 (reused as O later)
    ushort* wqkb = xb   + (size_t)Mtot * E;    // 2048x1024 (Wq rows 0-1023, Wk rows 1024-2047)
    ushort* wvb  = wqkb + (size_t)2 * H * E;
    ushort* wob  = wvb  + (size_t)H * E;
    ushort* qk   = wob  + (size_t)H * H;       // 8192x2048 (Q cols 0-1023, K cols 1024-2047)
    ushort* vt   = qk   + (size_t)Mtot * 2 * H;// 1024 x 8192  (VT[h][b*S+s])
    ushort* P    = vt   + (size_t)H * Mtot;    // 4 x 2048 x 2048
    float*  bqk  = (float*)(P + (size_t)Bz * S * S); // 2048 fp32
    ushort* O    = xb;                         // reuse (xb dead after VT-proj)

    convert_f32_bf16<<<2048, 256, 0, stream>>>(x,  xb,   (long)Mtot * E);
    convert_f32_bf16<<<512,  256, 0, stream>>>(Wq, wqkb, (long)H * E);
    convert_f32_bf16<<<512,  256, 0, stream>>>(Wk, wqkb + (size_t)H * E, (long)H * E);
    convert_f32_bf16<<<512,  256, 0, stream>>>(Wv, wvb,  (long)H * E);
    convert_f32_bf16<<<512,  256, 0, stream>>>(Wo, wob,  (long)H * H);
    hipMemcpyAsync(bqk,     bq, H * sizeof(float), hipMemcpyDeviceToDevice, stream);
    hipMemcpyAsync(bqk + H, bk, H * sizeof(float), hipMemcpyDeviceToDevice, stream);

    // fused [Q|K] = x @ [Wq|Wk]^T + [bq|bk]   (256 blocks = full GPU)
    gemm256<true, false, false, false, ushort><<<dim3(8, 32, 1), 512, 0, stream>>>(
        xb, wqkb, qk, bqk, E, E, E, 2 * H, 0, 0, 0, 1.0f);
    // VT = Wv @ x^T + bv(row)  -> V transposed for free
    gemm256<false, true, false, false, ushort><<<dim3(32, 4, 1), 512, 0, stream>>>(
        wvb, xb, vt, bv, E, E, E, Mtot, 0, 0, 0, 1.0f);

    rope_inplace<<<Mtot, 256, 0, stream>>>(qk, pos);

    // P = causal_mask(Q@K^T / 32)
    gemm256<false, false, true, false, ushort><<<dim3(8, 8, Bz), 512, 0, stream>>>(
        qk, qk + H, P, nullptr, H, 2 * H, 2 * H, S,
        (long)S * 2 * H, (long)S * 2 * H, (long)S * S, 0.03125f);

    softmax_rows<<<Mtot, 256, 0, stream>>>(P);

    // O = P @ VT^T  (K clipped by causality to rowBase+256)
    gemm256<false, false, false, true, ushort><<<dim3(4, 8, Bz), 512, 0, stream>>>(
        P, vt, O, nullptr, S, S, Mtot, H,
        (long)S * S, (long)S, (long)S * H, 1.0f);

    // out = O @ Wo^T + bo  (fp32 -> d_out)
    gemm256<true, false, false, false, float><<<dim3(4, 32, 1), 512, 0, stream>>>(
        O, wob, out, bo, H, H, H, H, 0, 0, 0, 1.0f);
}

// Round 5
// 342.217 us; speedup vs baseline: 1.1786x; 1.1177x over previous
//
#include <hip/hip_runtime.h>
#include <hip/hip_bf16.h>
#include <stdint.h>

typedef __attribute__((ext_vector_type(4))) float  f32x4;
typedef __attribute__((ext_vector_type(8))) short  short8;
typedef __attribute__((ext_vector_type(8))) __bf16 bf16x8;

#define GLB_AS __attribute__((address_space(1)))
#define LDS_AS __attribute__((address_space(3)))

__device__ __forceinline__ float bf2f(ushort u) {
    union { uint u32; float f; } c; c.u32 = (uint)u << 16; return c.f;
}
__device__ __forceinline__ ushort f2bf(float f) {
    union { float f; uint u32; } c; c.f = f;
    uint x = c.u32;
    return (ushort)((x + 0x7fffu + ((x >> 16) & 1u)) >> 16);
}

__device__ __forceinline__ void storeC(float* p, float v)  { *p = v; }
__device__ __forceinline__ void storeC(ushort* p, float v) { *p = f2bf(v); }

template<int N> __device__ __forceinline__ void vmwait() {
    if constexpr (N == 0) asm volatile("s_waitcnt vmcnt(0)" ::: "memory");
    else if constexpr (N == 6) asm volatile("s_waitcnt vmcnt(6)" ::: "memory");
}

// ---------------- fp32 -> bf16 convert ----------------
__global__ __launch_bounds__(256) void convert_f32_bf16(
    const float* __restrict__ in, ushort* __restrict__ out, long n)
{
    long i0 = ((long)blockIdx.x * 256 + threadIdx.x) * 8;
    long stride = (long)gridDim.x * 256 * 8;
    for (long i = i0; i < n; i += stride) {
        float4 a = *(const float4*)(in + i);
        float4 b = *(const float4*)(in + i + 4);
        short8 o;
        o[0] = (short)f2bf(a.x); o[1] = (short)f2bf(a.y);
        o[2] = (short)f2bf(a.z); o[3] = (short)f2bf(a.w);
        o[4] = (short)f2bf(b.x); o[5] = (short)f2bf(b.y);
        o[6] = (short)f2bf(b.z); o[7] = (short)f2bf(b.w);
        *(short8*)(out + i) = o;
    }
}

// ---------------- RoPE in-place on fused QK buffer [8192][2048] ----------------
__global__ __launch_bounds__(256) void rope_inplace(
    ushort* __restrict__ qk, const float* __restrict__ pos)
{
    const int row = blockIdx.x;
    const float p = pos[row];
    const size_t base = (size_t)row * 2048;
    const int tid = threadIdx.x;
#pragma unroll
    for (int t = 0; t < 2; ++t) {
        int j = tid + t * 256;                       // pair index 0..511
        float omega = exp2f(-(float)j * (13.287712379549449f / 512.0f));
        float ang = p * omega;
        float sn, cs;
        sincosf(ang, &sn, &cs);
        uint pq = *(uint*)(qk + base + 2 * j);
        float q0 = bf2f((ushort)(pq & 0xffff)), q1 = bf2f((ushort)(pq >> 16));
        float r0 = q0 * cs - q1 * sn, r1 = q1 * cs + q0 * sn;
        *(uint*)(qk + base + 2 * j) = (uint)f2bf(r0) | ((uint)f2bf(r1) << 16);
        uint pk = *(uint*)(qk + base + 1024 + 2 * j);
        float k0 = bf2f((ushort)(pk & 0xffff)), k1 = bf2f((ushort)(pk >> 16));
        float s0 = k0 * cs - k1 * sn, s1 = k1 * cs + k0 * sn;
        *(uint*)(qk + base + 1024 + 2 * j) = (uint)f2bf(s0) | ((uint)f2bf(s1) << 16);
    }
}

// ---------------- row softmax over 2048 bf16, in place ----------------
__global__ __launch_bounds__(256) void softmax_rows(ushort* __restrict__ P)
{
    const size_t base = (size_t)blockIdx.x * 2048;
    const int tid = threadIdx.x;
    const int lane = tid & 63, wid = tid >> 6;
    short8 v = *(const short8*)(P + base + tid * 8);
    float f[8];
#pragma unroll
    for (int j = 0; j < 8; ++j) f[j] = bf2f((ushort)v[j]);
    float mx = f[0];
#pragma unroll
    for (int j = 1; j < 8; ++j) mx = fmaxf(mx, f[j]);
#pragma unroll
    for (int o = 32; o; o >>= 1) mx = fmaxf(mx, __shfl_xor(mx, o, 64));
    __shared__ float redm[4], reds[4];
    if (lane == 0) redm[wid] = mx;
    __syncthreads();
    mx = fmaxf(fmaxf(redm[0], redm[1]), fmaxf(redm[2], redm[3]));
    float s = 0.f;
#pragma unroll
    for (int j = 0; j < 8; ++j) { f[j] = __expf(f[j] - mx); s += f[j]; }
#pragma unroll
    for (int o = 32; o; o >>= 1) s += __shfl_xor(s, o, 64);
    if (lane == 0) reds[wid] = s;
    __syncthreads();
    s = reds[0] + reds[1] + reds[2] + reds[3];
    float inv = 1.0f / s;
    short8 o8;
#pragma unroll
    for (int j = 0; j < 8; ++j) o8[j] = (short)f2bf(f[j] * inv);
    *(short8*)(P + base + tid * 8) = o8;
}

// ================= 128x128 m97-style bf16 GEMM (C = A @ B^T) =================
// 256 thr / 4 waves, BK=64, 32 KiB LDS -> 2 blocks/CU. For narrow grids.
template<bool BIAS_COL, bool BIAS_ROW, bool CAUSAL_MASK, bool CAUSAL_K, typename OutT>
__global__ __launch_bounds__(256, 2) void gemm_bt(
    const ushort* __restrict__ A, const ushort* __restrict__ B,
    OutT* __restrict__ C, const float* __restrict__ bias,
    int K, int lda, int ldb, int ldc,
    long sA, long sB, long sC, float scale)
{
    __shared__ ushort As[128 * 64];
    __shared__ ushort Bs[128 * 64];
    A += (long)blockIdx.z * sA;
    B += (long)blockIdx.z * sB;
    C += (long)blockIdx.z * sC;
    const int tid = threadIdx.x;
    const int lane = tid & 63;
    const int wid = tid >> 6;
    const int rowBase = blockIdx.y * 128;
    const int colBase = blockIdx.x * 128;
    const int wr = (wid >> 1) * 64;
    const int wc = (wid & 1) * 64;
    const int fr = lane & 15;
    const int kg = lane >> 4;

    f32x4 acc[4][4] = {};

    bool skip = false;
    if (CAUSAL_MASK) skip = (colBase > rowBase + 127);
    int Kend = K;
    if (CAUSAL_K) { int ke = rowBase + 128; Kend = ke < K ? ke : K; }

    if (!skip) {
        const int sRow = lane >> 3;
        const int sCol = (lane & 7) * 8;
        for (int k0 = 0; k0 < Kend; k0 += 64) {
            __syncthreads();
#pragma unroll
            for (int r = 0; r < 4; ++r) {
                const int chunk = wid * 4 + r;
                const ushort* ga = A + (size_t)(rowBase + chunk * 8 + sRow) * lda + k0 + sCol;
                __builtin_amdgcn_global_load_lds((const GLB_AS void*)ga,
                    (LDS_AS void*)(As + chunk * 512), 16, 0, 0);
                const ushort* gb = B + (size_t)(colBase + chunk * 8 + sRow) * ldb + k0 + sCol;
                __builtin_amdgcn_global_load_lds((const GLB_AS void*)gb,
                    (LDS_AS void*)(Bs + chunk * 512), 16, 0, 0);
            }
            __syncthreads();
#pragma unroll
            for (int kk = 0; kk < 64; kk += 32) {
                short8 a[4], b[4];
#pragma unroll
                for (int m = 0; m < 4; ++m)
                    a[m] = *(const short8*)&As[(wr + m * 16 + fr) * 64 + kk + kg * 8];
#pragma unroll
                for (int n = 0; n < 4; ++n)
                    b[n] = *(const short8*)&Bs[(wc + n * 16 + fr) * 64 + kk + kg * 8];
#pragma unroll
                for (int m = 0; m < 4; ++m)
#pragma unroll
                    for (int n = 0; n < 4; ++n)
                        acc[m][n] = __builtin_amdgcn_mfma_f32_16x16x32_bf16(
                            __builtin_bit_cast(bf16x8, a[m]),
                            __builtin_bit_cast(bf16x8, b[n]),
                            acc[m][n], 0, 0, 0);
            }
        }
    }

#pragma unroll
    for (int m = 0; m < 4; ++m) {
#pragma unroll
        for (int n = 0; n < 4; ++n) {
#pragma unroll
            for (int j = 0; j < 4; ++j) {
                int row = rowBase + wr + m * 16 + kg * 4 + j;
                int col = colBase + wc + n * 16 + fr;
                float v = acc[m][n][j] * scale;
                if (BIAS_COL) v += bias[col];
                if (BIAS_ROW) v += bias[row];
                if (CAUSAL_MASK && (col > row)) v = -1e7f;
                storeC(C + (size_t)row * ldc + col, v);
            }
        }
    }
}

// ================= 256x256 8-phase bf16 GEMM (C = A @ B^T) =================
// 512 thr / 8 waves (2M x 4N). BK=64. Double-buffered 128 KiB LDS.
// 3-bit XOR swizzle (LDS chunk j of row r holds global chunk j^(r&7)).
// One vmcnt(6) per tile at p4; A held in split reg sets so p4 issues no reads.

template<int BUF, int HALF>
__device__ __forceinline__ void stageT(ushort (&L)[2][2][8192],
    const ushort* __restrict__ G, int tileBase, int ld, int tk,
    int wid, int sr, int scS)
{
#pragma unroll
    for (int i = 0; i < 2; ++i) {
        const int chunk = wid * 2 + i;
        const ushort* g = G + (size_t)(tileBase + HALF * 128 + chunk * 8 + sr) * ld
                        + tk * 64 + scS * 8;
        __builtin_amdgcn_global_load_lds((const GLB_AS void*)g,
            (LDS_AS void*)(&L[BUF][HALF][chunk * 512]), 16, 0, 0);
    }
}

template<int BUF, int HALF>
__device__ __forceinline__ void readA(const ushort (&As)[2][2][8192],
    short8 (&afr)[4][2], int wr, int fr, int kg)
{
    const int sw = (fr & 7) << 3;
#pragma unroll
    for (int m = 0; m < 4; ++m) {
        const int r = wr * 64 + m * 16 + fr;
#pragma unroll
        for (int kk = 0; kk < 2; ++kk)
            afr[m][kk] = *(const short8*)&As[BUF][HALF][r * 64 + ((kk * 32 + kg * 8) ^ sw)];
    }
}

template<int BUF, int HALF>
__device__ __forceinline__ void readB(const ushort (&Bs)[2][2][8192],
    short8 (&bfr)[2][2], int wc, int fr, int kg)
{
    const int sw = (fr & 7) << 3;
#pragma unroll
    for (int n = 0; n < 2; ++n) {
        const int r = wc * 32 + n * 16 + fr;
#pragma unroll
        for (int kk = 0; kk < 2; ++kk)
            bfr[n][kk] = *(const short8*)&Bs[BUF][HALF][r * 64 + ((kk * 32 + kg * 8) ^ sw)];
    }
}

template<int MQ, int NQ>
__device__ __forceinline__ void domfma(f32x4 (&acc)[2][2][4][2],
    const short8 (&afr)[4][2], const short8 (&bfr)[2][2])
{
#pragma unroll
    for (int kk = 0; kk < 2; ++kk)
#pragma unroll
        for (int m = 0; m < 4; ++m)
#pragma unroll
            for (int n = 0; n < 2; ++n)
                acc[MQ][NQ][m][n] = __builtin_amdgcn_mfma_f32_16x16x32_bf16(
                    __builtin_bit_cast(bf16x8, afr[m][kk]),
                    __builtin_bit_cast(bf16x8, bfr[n][kk]),
                    acc[MQ][NQ][m][n], 0, 0, 0);
}

#define PHASE_MID() \
    __builtin_amdgcn_s_barrier(); \
    asm volatile("s_waitcnt lgkmcnt(0)" ::: "memory"); \
    __builtin_amdgcn_s_setprio(1)
#define PHASE_END() \
    __builtin_amdgcn_s_setprio(0); \
    __builtin_amdgcn_s_barrier()

// MODE: 0 = FULL (stage A0(t+1) + tile t+2, vmcnt(6))
//       1 = PRELAST (stage A0(t+1) only, vmcnt(0))
//       2 = LAST (no stages, no waits)
template<int BUF, int MODE>
__device__ __forceinline__ void group(
    ushort (&As)[2][2][8192], ushort (&Bs)[2][2][8192],
    f32x4 (&acc)[2][2][4][2],
    const ushort* __restrict__ A, const ushort* __restrict__ B,
    int rowBase, int colBase, int lda, int ldb, int t,
    int wid, int wr, int wc, int fr, int kg, int sr, int scS)
{
    short8 afrA[4][2], afrB[4][2], bfr[2][2];
    // p1: read A0,B0; stage A0(t+1)
    readA<BUF, 0>(As, afrA, wr, fr, kg);
    readB<BUF, 0>(Bs, bfr, wc, fr, kg);
    if constexpr (MODE != 2) stageT<BUF ^ 1, 0>(As, A, rowBase, lda, t + 1, wid, sr, scS);
    asm volatile("s_waitcnt lgkmcnt(8)" ::: "memory");
    PHASE_MID();
    domfma<0, 0>(acc, afrA, bfr);
    PHASE_END();
    // p2: read A1; stage B0(t+2)
    readA<BUF, 1>(As, afrB, wr, fr, kg);
    if constexpr (MODE == 0) stageT<BUF, 0>(Bs, B, colBase, ldb, t + 2, wid, sr, scS);
    PHASE_MID();
    domfma<1, 0>(acc, afrB, bfr);
    PHASE_END();
    // p3: read B1; stage A1(t+2)
    readB<BUF, 1>(Bs, bfr, wc, fr, kg);
    if constexpr (MODE == 0) stageT<BUF, 1>(As, A, rowBase, lda, t + 2, wid, sr, scS);
    PHASE_MID();
    domfma<1, 1>(acc, afrB, bfr);
    PHASE_END();
    // p4: no reads; stage B1(t+2)
    if constexpr (MODE == 0) stageT<BUF, 1>(Bs, B, colBase, ldb, t + 2, wid, sr, scS);
    PHASE_MID();
    domfma<0, 1>(acc, afrA, bfr);
    __builtin_amdgcn_s_setprio(0);
    if constexpr (MODE == 0) vmwait<6>();
    else if constexpr (MODE == 1) vmwait<0>();
    __builtin_amdgcn_s_barrier();
}

template<bool BIAS_COL, bool CAUSAL_MASK, typename OutT>
__global__ __launch_bounds__(512, 1) void gemm256(
    const ushort* __restrict__ A, const ushort* __restrict__ B,
    OutT* __restrict__ C, const float* __restrict__ bias,
    int K, int lda, int ldb, int ldc,
    long sA, long sB, long sC, float scale)
{
    __shared__ ushort As[2][2][8192];   // [dbuf][half: rows 0-127 / 128-255][128r x 64k]
    __shared__ ushort Bs[2][2][8192];

    // T1: bijective XCD swizzle (all grids have nwg % 8 == 0)
    const int nx = gridDim.x, ny = gridDim.y;
    int flat = blockIdx.x + nx * (blockIdx.y + ny * blockIdx.z);
    const int nwg = nx * ny * gridDim.z;
    const int qq = nwg >> 3;
    int swz = (flat & 7) * qq + (flat >> 3);
    const int bx = swz % nx;
    int rest = swz / nx;
    const int by = rest % ny;
    const int bz = rest / ny;

    A += (long)bz * sA;
    B += (long)bz * sB;
    C += (long)bz * sC;
    const int tid = threadIdx.x;
    const int lane = tid & 63;
    const int wid = tid >> 6;
    const int wr = wid >> 2, wc = wid & 3;    // 2M x 4N waves
    const int rowBase = by * 256;
    const int colBase = bx * 256;
    const int fr = lane & 15;
    const int kg = lane >> 4;

    f32x4 acc[2][2][4][2] = {};

    const bool skip = CAUSAL_MASK && (colBase > rowBase + 255);

    if (!skip) {
        const int sr = lane >> 3;                  // row within 8-row chunk
        const int scS = (lane & 7) ^ (lane >> 3);  // inverse-swizzled src 16B-chunk
        // prologue: tile 0 fully + B0,A1,B1 of tile 1  (A0(1) staged at [0,p1])
        stageT<0, 0>(As, A, rowBase, lda, 0, wid, sr, scS);
        stageT<0, 0>(Bs, B, colBase, ldb, 0, wid, sr, scS);
        stageT<0, 1>(As, A, rowBase, lda, 0, wid, sr, scS);
        stageT<0, 1>(Bs, B, colBase, ldb, 0, wid, sr, scS);
        stageT<1, 0>(Bs, B, colBase, ldb, 1, wid, sr, scS);
        stageT<1, 1>(As, A, rowBase, lda, 1, wid, sr, scS);
        stageT<1, 1>(Bs, B, colBase, ldb, 1, wid, sr, scS);
        vmwait<6>();                               // tile 0 fully landed
        __builtin_amdgcn_s_barrier();

        const int NT = K >> 6;                     // even, >= 4 for our shapes
        int t = 0;
        for (; t + 3 < NT; t += 2) {
            group<0, 0>(As, Bs, acc, A, B, rowBase, colBase, lda, ldb, t,
                        wid, wr, wc, fr, kg, sr, scS);
            group<1, 0>(As, Bs, acc, A, B, rowBase, colBase, lda, ldb, t + 1,
                        wid, wr, wc, fr, kg, sr, scS);
        }
        group<0, 1>(As, Bs, acc, A, B, rowBase, colBase, lda, ldb, t,
                    wid, wr, wc, fr, kg, sr, scS);
        group<1, 2>(As, Bs, acc, A, B, rowBase, colBase, lda, ldb, t + 1,
                    wid, wr, wc, fr, kg, sr, scS);
    }

    // epilogue: C/D frag layout col = lane&15, row = (lane>>4)*4 + j
#pragma unroll
    for (int mq = 0; mq < 2; ++mq)
#pragma unroll
        for (int nq = 0; nq < 2; ++nq)
#pragma unroll
            for (int m = 0; m < 4; ++m)
#pragma unroll
                for (int n = 0; n < 2; ++n)
#pragma unroll
                    for (int j = 0; j < 4; ++j) {
                        int row = rowBase + mq * 128 + wr * 64 + m * 16 + kg * 4 + j;
                        int col = colBase + nq * 128 + wc * 32 + n * 16 + fr;
                        float v = acc[mq][nq][m][n][j] * scale;
                        if (BIAS_COL) v += bias[col];
                        if (CAUSAL_MASK && (col > row)) v = -1e7f;
                        storeC(C + (size_t)row * ldc + col, v);
                    }
}

// ---------------- host-side orchestration ----------------
extern "C" void kernel_launch(void* const* d_in, const int* in_sizes, int n_in,
                              void* d_out, int out_size, void* d_ws, size_t ws_size,
                              hipStream_t stream)
{
    const float* x   = (const float*)d_in[0];
    const float* pos = (const float*)d_in[1];
    // d_in[2] = mask (causal, known analytically) — unused
    const float* Wq = (const float*)d_in[3]; const float* bq = (const float*)d_in[4];
    const float* Wk = (const float*)d_in[5]; const float* bk = (const float*)d_in[6];
    const float* Wv = (const float*)d_in[7]; const float* bv = (const float*)d_in[8];
    const float* Wo = (const float*)d_in[9]; const float* bo = (const float*)d_in[10];
    float* out = (float*)d_out;

    const int S = 2048, E = 1024, H = 1024, Bz = 4;
    const int Mtot = Bz * S;   // 8192

    ushort* xb   = (ushort*)d_ws;              // 8192x1024 (reused as O later)
    ushort* wqkb = xb   + (size_t)Mtot * E;    // 2048x1024 (Wq rows 0-1023, Wk rows 1024-2047)
    ushort* wvb  = wqkb + (size_t)2 * H * E;
    ushort* wob  = wvb  + (size_t)H * E;
    ushort* qk   = wob  + (size_t)H * H;       // 8192x2048 (Q cols 0-1023, K cols 1024-2047)
    ushort* vt   = qk   + (size_t)Mtot * 2 * H;// 1024 x 8192  (VT[h][b*S+s])
    ushort* P    = vt   + (size_t)H * Mtot;    // 4 x 2048 x 2048
    float*  bqk  = (float*)(P + (size_t)Bz * S * S); // 2048 fp32
    ushort* O    = xb;                         // reuse (xb dead after VT-proj)

    convert_f32_bf16<<<2048, 256, 0, stream>>>(x,  xb,   (long)Mtot * E);
    convert_f32_bf16<<<512,  256, 0, stream>>>(Wq, wqkb, (long)H * E);
    convert_f32_bf16<<<512,  256, 0, stream>>>(Wk, wqkb + (size_t)H * E, (long)H * E);
    convert_f32_bf16<<<512,  256, 0, stream>>>(Wv, wvb,  (long)H * E);
    convert_f32_bf16<<<512,  256, 0, stream>>>(Wo, wob,  (long)H * H);
    hipMemcpyAsync(bqk,     bq, H * sizeof(float), hipMemcpyDeviceToDevice, stream);
    hipMemcpyAsync(bqk + H, bk, H * sizeof(float), hipMemcpyDeviceToDevice, stream);

    // fused [Q|K] = x @ [Wq|Wk]^T + [bq|bk]   (256 blocks = full GPU, 8-phase)
    gemm256<true, false, ushort><<<dim3(8, 32, 1), 512, 0, stream>>>(
        xb, wqkb, qk, bqk, E, E, E, 2 * H, 0, 0, 0, 1.0f);
    // VT = Wv @ x^T + bv(row)  -> V transposed for free (128^2, 512 blocks)
    gemm_bt<false, true, false, false, ushort><<<dim3(64, 8, 1), 256, 0, stream>>>(
        wvb, xb, vt, bv, E, E, E, Mtot, 0, 0, 0, 1.0f);

    rope_inplace<<<Mtot, 256, 0, stream>>>(qk, pos);

    // P = causal_mask(Q@K^T / 32)   (8-phase, 256 blocks)
    gemm256<false, true, ushort><<<dim3(8, 8, Bz), 512, 0, stream>>>(
        qk, qk + H, P, nullptr, H, 2 * H, 2 * H, S,
        (long)S * 2 * H, (long)S * 2 * H, (long)S * S, 0.03125f);

    softmax_rows<<<Mtot, 256, 0, stream>>>(P);

    // O = P @ VT^T  (K clipped by causality; 128^2, 512 blocks)
    gemm_bt<false, false, false, true, ushort><<<dim3(8, 16, Bz), 256, 0, stream>>>(
        P, vt, O, nullptr, S, S, Mtot, H,
        (long)S * S, (long)S, (long)S * H, 1.0f);

    // out = O @ Wo^T + bo  (fp32 -> d_out; 128^2, 512 blocks)
    gemm_bt<true, false, false, false, float><<<dim3(8, 64, 1), 256, 0, stream>>>(
        O, wob, out, bo, H, H, H, H, 0, 0, 0, 1.0f);
}